// Round 6
// baseline (367.474 us; speedup 1.0000x reference)
//
#include <hip/hip_runtime.h>
#include <hip/hip_bf16.h>
#include <cstdint>

// ---------------------------------------------------------------------------
// Hamilton_V5  R15:
//  - A3 K-loop has ZERO LDS and ZERO barriers: both operands are loaded
//    directly L2->registers as pre-swizzled MFMA fragments.
//    Fragment layout (per 32-row x 64-k block, 2KB chunk):
//      byte[(khalf*32 + row)*32 + kin] = M[R*32+row][T*64 + khalf*32 + kin]
//    so lane l's 32B operand slice = chunk + l*32 (2 coalesced dwordx4).
//    Chunk addr = ((R * 16) + T) * 2048   (16 = K/64 k-blocks).
//  - Producers emit these layouts directly:
//      * aw3t_body: same 128x128 LDS transpose, drain retargeted to
//        fragment addresses (Aw3T8F, 16MB).
//      * gemm64 EPI 4: h2 fragment-major fp8 bytes (h2F, 4MB).
//  - a3 K-loop: even/odd double-buffered register sets (static indexing),
//    12 loads + 8 mfma per step; compiler auto-inserts exact vmcnt.
//  - hbwd / L0 / L1 / L2 GEMMs unchanged from R14.
// ---------------------------------------------------------------------------

typedef __bf16 bf16_t;
typedef __bf16 bf16x4_t __attribute__((ext_vector_type(4)));
typedef __bf16 bf16x8_t __attribute__((ext_vector_type(8)));
typedef float f32x4_t __attribute__((ext_vector_type(4)));
typedef float f32x16_t __attribute__((ext_vector_type(16)));
typedef int intx4_t __attribute__((ext_vector_type(4)));
typedef int intx8_t __attribute__((ext_vector_type(8)));

#define DIMD 128
#define NROW 4096
#define SMEM_G64 24576     // gemm64 3-buf (3*4096*2) ; aw3t 16896 fits
#define SMEM3_BYTES 24576  // hbwd 3-buf only; a3 uses no LDS

// branchless tanh: t=2^(2x*log2e); tanh=1-2/(t+1).
__device__ __forceinline__ float fast_tanh(float x) {
  float t = __builtin_amdgcn_exp2f(x * 2.8853900817779268f);
  return 1.f - 2.f * __builtin_amdgcn_rcpf(t + 1.f);
}

// f32 -> fp8 e4m3 (OCP), RNE+sat via HW cvt
__device__ __forceinline__ uint8_t to_fp8(float x) {
  return (uint8_t)(__builtin_amdgcn_cvt_pk_fp8_f32(x, x, 0, false) & 0xff);
}

// pack 4 f32 -> 4 fp8 bytes (byte0=a .. byte3=d) via 2 HW cvt_pk
__device__ __forceinline__ uint32_t pk4_fp8(float a, float b, float c,
                                            float d) {
  uint32_t lo = (uint32_t)__builtin_amdgcn_cvt_pk_fp8_f32(a, b, 0, false);
  return (uint32_t)__builtin_amdgcn_cvt_pk_fp8_f32(c, d, lo, true);
}

// async global->LDS, 16B per lane; LDS dest = wave-uniform base + lane*16
__device__ __forceinline__ void g2l16(const void* gp, void* lp) {
  __builtin_amdgcn_global_load_lds(
      reinterpret_cast<__attribute__((address_space(1))) void*>(
          reinterpret_cast<uintptr_t>(gp)),
      reinterpret_cast<__attribute__((address_space(3))) void*>(
          reinterpret_cast<uintptr_t>(lp)),
      16, 0, 0);
}

// DPP accumulating add (VALU pipe -- no LDS). bound_ctrl=1 => 0-fill.
template <int CTRL>
__device__ __forceinline__ float dpp_addf(float v) {
  return v + __int_as_float(__builtin_amdgcn_update_dpp(
                 0, __float_as_int(v), CTRL, 0xf, 0xf, true));
}
// sum over each 32-lane half; result in lane 31 (half 0) / lane 63 (half 1).
__device__ __forceinline__ float dpp_sum32(float v) {
  v = dpp_addf<0x111>(v);  // row_shr:1
  v = dpp_addf<0x112>(v);  // row_shr:2
  v = dpp_addf<0x114>(v);  // row_shr:4
  v = dpp_addf<0x118>(v);  // row_shr:8  -> lane15/31/47/63 = row sums
  v = dpp_addf<0x142>(v);  // row_bcast15 -> lane31/63 = 32-lane sums
  return v;
}

// ---------------------------------------------------------------------------
// bf16 GEMM, 64x64 tile, BK=32, 4 waves 2x2 (each 32x32 = 2x2 mfma 16x16x32).
// Triple-buffered LDS, depth-2 prefetch, counted vmcnt(2) per step.
// EPI 0: bf16 tanh(C+b); EPI 4: fp8 x64 fragment-major (h2F).
// ---------------------------------------------------------------------------
template <int EPI>
__device__ __forceinline__ void gemm64_body(char* smem, int bx, int by,
                                            const bf16_t* A, int lda,
                                            const bf16_t* B, int ldb, int K,
                                            const float* bias, void* outp,
                                            int ldo) {
  constexpr int BK = 32;
  bf16_t* As = (bf16_t*)smem;   // 3 x 64*32
  bf16_t* Bs = As + 3 * 2048;   // 3 x 64*32
  const int NT = K / BK;

  const int m0 = bx * 64;
  const int n0 = by * 64;
  const int tid = threadIdx.x;
  const int wave = tid >> 6;
  const int lane = tid & 63;
  const int wm = wave >> 1;
  const int wn = wave & 1;

  const int sr = lane >> 2;
  const int sk = (((lane & 3) ^ ((sr >> 1) & 3)) * 8);
  const int fr = lane & 15;
  const int fk = (((lane >> 4) ^ ((fr >> 1) & 3)) * 8);
  const int rb = wave * 16;  // each wave stages 16 rows of A and B

  const bf16_t* Ag = A + (size_t)(m0 + rb + sr) * lda + sk;
  const bf16_t* Bg = B + (size_t)(n0 + rb + sr) * ldb + sk;

#define G64_STAGE(buf, k0)                              \
  do {                                                  \
    g2l16(Ag + (k0), As + (buf) * 2048 + rb * BK);      \
    g2l16(Bg + (k0), Bs + (buf) * 2048 + rb * BK);      \
  } while (0)

  f32x4_t acc[2][2] = {};

  G64_STAGE(0, 0);
  G64_STAGE(1, BK);
  asm volatile("s_waitcnt vmcnt(2)" ::: "memory");
  __builtin_amdgcn_s_barrier();
  asm volatile("" ::: "memory");

  for (int t = 0; t < NT; ++t) {
    if (t + 2 < NT) G64_STAGE((t + 2) % 3, (t + 2) * BK);
    const bf16_t* Ab = As + (t % 3) * 2048;
    const bf16_t* Bb = Bs + (t % 3) * 2048;

    bf16x8_t af[2], bb[2];
#pragma unroll
    for (int u = 0; u < 2; ++u) {
      af[u] = *(const bf16x8_t*)(Ab + (wm * 32 + u * 16 + fr) * BK + fk);
      bb[u] = *(const bf16x8_t*)(Bb + (wn * 32 + u * 16 + fr) * BK + fk);
    }
#pragma unroll
    for (int i = 0; i < 2; ++i)
#pragma unroll
      for (int j = 0; j < 2; ++j)
        acc[i][j] = __builtin_amdgcn_mfma_f32_16x16x32_bf16(af[i], bb[j],
                                                            acc[i][j], 0, 0, 0);
    if (t < NT - 1) {
      if (t + 2 < NT)
        asm volatile("s_waitcnt vmcnt(2)" ::: "memory");
      else
        asm volatile("s_waitcnt vmcnt(0)" ::: "memory");
      __builtin_amdgcn_s_barrier();
      asm volatile("" ::: "memory");
    }
  }
#undef G64_STAGE

  // C/D layout (m89): col = lane&15, row = (lane>>4)*4 + reg
#pragma unroll
  for (int i = 0; i < 2; ++i) {
    const int row = m0 + wm * 32 + i * 16 + (lane >> 4) * 4;
#pragma unroll
    for (int j = 0; j < 2; ++j) {
      const int col = n0 + wn * 32 + j * 16 + fr;
      if constexpr (EPI == 0) {
        bf16_t* O = (bf16_t*)outp;
        const float b = bias[col];
#pragma unroll
        for (int r = 0; r < 4; ++r)
          O[(size_t)(row + r) * ldo + col] = (bf16_t)fast_tanh(acc[i][j][r] + b);
      } else {  // EPI 4: h2 fragment-major fp8
        uint8_t* O = (uint8_t*)outp;
        const float b = bias[col];
        const int kb = col >> 6;
        const int khalf = (col >> 5) & 1;
        const int kin = col & 31;
#pragma unroll
        for (int r = 0; r < 4; ++r) {
          const int rw = row + r;
          O[(size_t)((rw >> 5) * 16 + kb) * 2048 +
            (khalf * 32 + (rw & 31)) * 32 + kin] =
              to_fp8(64.f * fast_tanh(acc[i][j][r] + b));
        }
      }
    }
  }
}

// ---------------------------------------------------------------------------
// Hbwd bf16 GEMM for 512-thread launch: 64x64 tile, BK=32, 8 waves arranged
// 2x4; per-wave 32x16 = 2x1 mfma 16x16x32.  dx store / dv atomicAdd(-C).
// Triple-buffer/counted-vmcnt pipeline (1 stage op per wave).
// ---------------------------------------------------------------------------
__device__ __forceinline__ void hbwd64_body(char* smem, int bx, int by,
                                            const bf16_t* A, int lda,
                                            const bf16_t* B, int ldb, int K,
                                            float* out, int ldo) {
  constexpr int BK = 32;
  bf16_t* As = (bf16_t*)smem;  // 3 x 64*32
  bf16_t* Bs = As + 3 * 2048;
  const int NT = K / BK;  // 20

  const int m0 = bx * 64;
  const int n0 = by * 64;
  const int tid = threadIdx.x;
  const int wave = tid >> 6;  // 0..7
  const int lane = tid & 63;
  const int wm = wave >> 2;   // 0..1
  const int wn = wave & 3;    // 0..3

  const int sr = lane >> 2;
  const int sk = (((lane & 3) ^ ((sr >> 1) & 3)) * 8);
  const int fr = lane & 15;
  const int fk = (((lane >> 4) ^ ((fr >> 1) & 3)) * 8);

  // waves 0..3 stage A rows, 4..7 stage B rows (1 g2l16 per wave per step)
  const int rbs = (wave & 3) * 16;
  const bf16_t* Sg = (wave < 4) ? A + (size_t)(m0 + rbs + sr) * lda + sk
                                : B + (size_t)(n0 + rbs + sr) * ldb + sk;
  bf16_t* Sl = ((wave < 4) ? As : Bs) + rbs * BK;

  f32x4_t acc[2] = {};

  g2l16(Sg, Sl);
  g2l16(Sg + BK, Sl + 2048);
  asm volatile("s_waitcnt vmcnt(1)" ::: "memory");
  __builtin_amdgcn_s_barrier();
  asm volatile("" ::: "memory");

  for (int t = 0; t < NT; ++t) {
    if (t + 2 < NT) g2l16(Sg + (t + 2) * BK, Sl + ((t + 2) % 3) * 2048);
    const bf16_t* Ab = As + (t % 3) * 2048;
    const bf16_t* Bb = Bs + (t % 3) * 2048;

    const bf16x8_t bb = *(const bf16x8_t*)(Bb + (wn * 16 + fr) * BK + fk);
#pragma unroll
    for (int u = 0; u < 2; ++u) {
      const bf16x8_t af =
          *(const bf16x8_t*)(Ab + (wm * 32 + u * 16 + fr) * BK + fk);
      acc[u] = __builtin_amdgcn_mfma_f32_16x16x32_bf16(af, bb, acc[u], 0, 0, 0);
    }
    if (t < NT - 1) {
      if (t + 2 < NT)
        asm volatile("s_waitcnt vmcnt(1)" ::: "memory");
      else
        asm volatile("s_waitcnt vmcnt(0)" ::: "memory");
      __builtin_amdgcn_s_barrier();
      asm volatile("" ::: "memory");
    }
  }

  // C/D layout (m89): col = lane&15, row = (lane>>4)*4 + reg
  const bool dx = (n0 < DIMD);
  const int col = n0 + wn * 16 + fr;
#pragma unroll
  for (int t = 0; t < 2; ++t) {
    const int row = m0 + wm * 32 + t * 16 + (lane >> 4) * 4;
#pragma unroll
    for (int r = 0; r < 4; ++r) {
      const size_t idx = (size_t)(row + r) * ldo + col;
      if (dx) out[idx] = acc[t][r];
      else atomicAdd(&out[idx], -acc[t][r]);  // dv_H shares with dvA
    }
  }
}

// ---------------------------------------------------------------------------
// A3 fused GEMM, MX-fp8, R15: 512 threads / 8 waves, BM=256, BN=256, BK=64.
// Wave grid 4x2: each wave 64x128 via 2x4 mfma 32x32x64 (acc[2][4] f32x16).
// NO LDS, NO BARRIERS: operands loaded L2->reg as pre-swizzled fragments
// (AF = h2F 4MB, BF = Aw3T8F 16MB).  Even/odd double-buffered loads;
// compiler auto-vmcnt via data dependence.
// ---------------------------------------------------------------------------
__device__ __forceinline__ void a3_body(int bx, int by, const uint8_t* AF,
                                        const uint8_t* BF, float* out,
                                        const float* ab3, const float* uvec) {
  constexpr int NT = 16;  // K / 64
  const int tid = threadIdx.x;
  const int wave = tid >> 6;  // 0..7
  const int lane = tid & 63;
  const int wm = wave >> 1;   // 0..3 : 64-row strip
  const int wn = wave & 1;    // 0..1 : 128-col strip
  const int rl = lane & 31;
  const int m0 = bx * 256;
  const int n0 = by * 256;

  // fragment stream base pointers (lane's 32B slice of each 2KB chunk)
  const uint8_t* bp[6];
#pragma unroll
  for (int i = 0; i < 2; ++i)
    bp[i] = AF + (size_t)(bx * 8 + wm * 2 + i) * 16 * 2048 + lane * 32;
#pragma unroll
  for (int j = 0; j < 4; ++j)
    bp[2 + j] = BF + (size_t)(by * 8 + wn * 4 + j) * 16 * 2048 + lane * 32;

  f32x16_t acc[2][4] = {};
  intx4_t cur[12], nxt[12];

#define A3_LOADSET(dst, off)                                   \
  _Pragma("unroll") for (int q = 0; q < 6; ++q) {              \
    dst[2 * q] = *(const intx4_t*)(bp[q] + (off));             \
    dst[2 * q + 1] = *(const intx4_t*)(bp[q] + (off) + 16);    \
  }

#define A3_MFMASET(S)                                                         \
  _Pragma("unroll") for (int i = 0; i < 2; ++i) {                             \
    intx8_t af = __builtin_shufflevector(S[2 * i], S[2 * i + 1], 0, 1, 2, 3,  \
                                         4, 5, 6, 7);                         \
    _Pragma("unroll") for (int j = 0; j < 4; ++j) {                           \
      intx8_t bf = __builtin_shufflevector(S[4 + 2 * j], S[5 + 2 * j], 0, 1,  \
                                           2, 3, 4, 5, 6, 7);                 \
      acc[i][j] = __builtin_amdgcn_mfma_scale_f32_32x32x64_f8f6f4(            \
          af, bf, acc[i][j], 0, 0, 0, 0x79797979, 0, 0x79797979);             \
    }                                                                         \
  }

  A3_LOADSET(cur, 0);
#pragma unroll 1
  for (int t = 0; t < NT; t += 2) {
    A3_LOADSET(nxt, (size_t)(t + 1) * 2048);
    A3_MFMASET(cur);
    if (t + 2 < NT) A3_LOADSET(cur, (size_t)(t + 2) * 2048);
    A3_MFMASET(nxt);
  }
#undef A3_LOADSET
#undef A3_MFMASET

  // epilogue: C/D col = lane&31, row = (reg&3)+8*(reg>>2)+4*(lane>>5).
  // wave's 128 cols are one full u-period -> ONE out column 128+2by+wn.
  const int q = lane >> 5;
  float uu[4], b3[4];
#pragma unroll
  for (int j = 0; j < 4; ++j) {
    uu[j] = uvec[j * 32 + rl];
    b3[j] = ab3[n0 + wn * 128 + j * 32 + rl];
  }
  const int ocol = 128 + 2 * by + wn;
#pragma unroll
  for (int i = 0; i < 2; ++i) {
    float s16[16];
#pragma unroll
    for (int r = 0; r < 16; ++r) {
      float s = 0.f;
#pragma unroll
      for (int j = 0; j < 4; ++j) s += fast_tanh(acc[i][j][r] + b3[j]) * uu[j];
      s16[r] = s;
    }
#pragma unroll
    for (int r = 0; r < 16; ++r) s16[r] = dpp_sum32(s16[r]);
    if (rl == 31) {  // lanes 31 and 63 hold the two q-half sums
      const int rowb = m0 + wm * 64 + i * 32 + 4 * q;
#pragma unroll
      for (int r = 0; r < 16; ++r)
        atomicAdd(&out[(size_t)(rowb + (r & 3) + 8 * (r >> 2)) * 256 + ocol],
                  s16[r]);
    }
  }
}

// ---------------------------------------------------------------------------
// transposes / cvt helpers
// ---------------------------------------------------------------------------
__device__ __forceinline__ void tcvt_body(char* smem, const float* in,
                                          bf16_t* out, int R, int C, int bx,
                                          int by) {
  float(*t)[33] = (float(*)[33])smem;  // 4224 B
  const int c0 = bx * 32;
  const int r0 = by * 32;
  const int tx = threadIdx.x & 31;
  const int ty = threadIdx.x >> 5;
#pragma unroll
  for (int k = 0; k < 4; ++k)
    t[ty + k * 8][tx] = in[(size_t)(r0 + ty + k * 8) * C + c0 + tx];
  __syncthreads();
#pragma unroll
  for (int k = 0; k < 4; ++k)
    out[(size_t)(c0 + ty + k * 8) * R + r0 + tx] = (bf16_t)t[tx][ty + k * 8];
}

// Aw3 (1024 x 16384) -> fp8 x64, FRAGMENT-MAJOR (Aw3T8F).
// 128x128 tile per block (1024 blocks), float4 reads, cvt_pk packing,
// u32-transposed LDS [128][33]; drain writes fragment chunks:
//   chunk ((cb*16)+kb)*2048, byte (khalf*32 + col%32)*32 + k%32.
__device__ __forceinline__ void aw3t_body(char* smem, const float* Aw3,
                                          uint8_t* Aw3T8F, int b) {
  uint32_t(*T)[33] = (uint32_t(*)[33])smem;  // 16896 B
  const int ct = b & 127;
  const int rt = b >> 7;
  const size_t c0 = (size_t)ct * 128;
  const int r0 = rt * 128;
  const int tx = threadIdx.x & 31;  // col-chunk (4 f32)
  const int g = threadIdx.x >> 5;   // 0..7 row-group
#pragma unroll
  for (int k = 0; k < 4; ++k) {
    const int rr = r0 + 4 * g + 32 * k;
    const float4 v0 = *(const float4*)(Aw3 + (size_t)(rr + 0) * 16384 + c0 + 4 * tx);
    const float4 v1 = *(const float4*)(Aw3 + (size_t)(rr + 1) * 16384 + c0 + 4 * tx);
    const float4 v2 = *(const float4*)(Aw3 + (size_t)(rr + 2) * 16384 + c0 + 4 * tx);
    const float4 v3 = *(const float4*)(Aw3 + (size_t)(rr + 3) * 16384 + c0 + 4 * tx);
    const int r4 = g + 8 * k;  // row/4 within tile (k-dim of output)
    T[4 * tx + 0][r4] = pk4_fp8(64.f * v0.x, 64.f * v1.x, 64.f * v2.x, 64.f * v3.x);
    T[4 * tx + 1][r4] = pk4_fp8(64.f * v0.y, 64.f * v1.y, 64.f * v2.y, 64.f * v3.y);
    T[4 * tx + 2][r4] = pk4_fp8(64.f * v0.z, 64.f * v1.z, 64.f * v2.z, 64.f * v3.z);
    T[4 * tx + 3][r4] = pk4_fp8(64.f * v0.w, 64.f * v1.w, 64.f * v2.w, 64.f * v3.w);
  }
  __syncthreads();
  // T[cc][tx] = 4 fp8 bytes: col = c0+cc, k = r0+4*tx .. +3
  const int kb = (rt << 1) + (tx >> 4);     // k-block (64)
  const int khalf = (tx >> 3) & 1;          // k-half (32)
  const int kin = (tx & 7) << 2;            // k%32 (4-aligned)
#pragma unroll
  for (int k2 = 0; k2 < 16; ++k2) {
    const int cc = g + 8 * k2;
    const int cb = (ct << 2) + (cc >> 5);
    const int cin = cc & 31;
    *(uint32_t*)(Aw3T8F + (size_t)(cb * 16 + kb) * 2048 +
                 (khalf * 32 + cin) * 32 + kin) = T[cc][tx];
  }
}

// one wave handles one row: pre2 = h.Hw2; w_j = s*Hw2_j*(1-h_j^2)
__device__ __forceinline__ void hgrad_row(int row, const bf16_t* h,
                                          const float* Hw2, const float* Hb2,
                                          bf16_t* wout) {
  const int lane = threadIdx.x & 63;
  float hv[10], wv[10];
  float pre2 = 0.f;
#pragma unroll
  for (int t = 0; t < 10; ++t) {
    const int j = lane + t * 64;
    hv[t] = (float)h[(size_t)row * 640 + j];
    wv[t] = Hw2[j];
    pre2 += hv[t] * wv[t];
  }
#pragma unroll
  for (int d = 1; d < 64; d <<= 1) pre2 += __shfl_xor(pre2, d, 64);
  const float y = fast_tanh(pre2 + Hb2[0]);
  const float s = 1.f - y * y;
#pragma unroll
  for (int t = 0; t < 10; ++t) {
    const int j = lane + t * 64;
    wout[(size_t)row * 640 + j] = (bf16_t)(s * wv[t] * (1.f - hv[t] * hv[t]));
  }
}

// ---------------------------------------------------------------------------
// L0: inp cvt (1024) + Hw1T (160) + Aw1T (64) + Aw2T (512) + Hw1_bf cvt (160)
//     + zero-out (1024) = 2944 blocks
// ---------------------------------------------------------------------------
__global__ __launch_bounds__(256) void launch0(
    const float* __restrict__ inp, bf16_t* __restrict__ inp_bf,
    const float* __restrict__ Hw1, bf16_t* __restrict__ Hw1T,
    bf16_t* __restrict__ Hw1_bf, const float* __restrict__ Aw1,
    bf16_t* __restrict__ Aw1T, const float* __restrict__ Aw2,
    bf16_t* __restrict__ Aw2T, float* __restrict__ out) {
  __shared__ __align__(16) char smem[4224];
  int b = blockIdx.x;
  if (b < 1024) {
    const int i = b * 256 + threadIdx.x;
    const float4 v = ((const float4*)inp)[i];
    bf16x4_t o = {(bf16_t)v.x, (bf16_t)v.y, (bf16_t)v.z, (bf16_t)v.w};
    ((bf16x4_t*)inp_bf)[i] = o;
  } else if (b < 1184) {
    int s = b - 1024;
    tcvt_body(smem, Hw1, Hw1T, 256, 640, s % 20, s / 20);
  } else if (b < 1248) {
    int s = b - 1184;
    tcvt_body(smem, Aw1, Aw1T, 128, 512, s % 16, s / 16);
  } else if (b < 1760) {
    int s = b - 1248;
    tcvt_body(smem, Aw2, Aw2T, 512, 1024, s % 32, s / 32);
  } else if (b < 1920) {
    const int i = (b - 1760) * 256 + threadIdx.x;
    const float4 v = ((const float4*)Hw1)[i];
    bf16x4_t o = {(bf16_t)v.x, (bf16_t)v.y, (bf16_t)v.z, (bf16_t)v.w};
    ((bf16x4_t*)Hw1_bf)[i] = o;
  } else {
    const int i = (b - 1920) * 256 + threadIdx.x;
    ((float4*)out)[i] = make_float4(0.f, 0.f, 0.f, 0.f);
  }
}

// ---------------------------------------------------------------------------
// L1: Hfwd 64^2 (640) + A1 64^2 (512) + Aw3T tiles [0,512) = 1664 blocks
// ---------------------------------------------------------------------------
__global__ __launch_bounds__(256) void launch1(
    const bf16_t* __restrict__ inp_bf, const bf16_t* __restrict__ Hw1T,
    const float* __restrict__ Hb1, bf16_t* __restrict__ h_bf,
    const bf16_t* __restrict__ Aw1T, const float* __restrict__ Ab1,
    bf16_t* __restrict__ h1_bf, const float* __restrict__ Aw3,
    uint8_t* __restrict__ Aw3T8F) {
  __shared__ __align__(16) char smem[SMEM_G64];
  const int b = blockIdx.x;
  if (b < 640) {
    gemm64_body<0>(smem, b % 64, b / 64, inp_bf, 256, Hw1T, 256, 256, Hb1,
                   h_bf, 640);
  } else if (b < 1152) {
    const int i = b - 640;
    gemm64_body<0>(smem, i % 64, i / 64, inp_bf, 256, Aw1T, 128, 128, Ab1,
                   h1_bf, 512);
  } else {
    aw3t_body(smem, Aw3, Aw3T8F, b - 1152);  // tiles 0..511
  }
}

// ---------------------------------------------------------------------------
// L2: A2->h2F 64^2 (1024) + hgrad (1024) + Aw3T tiles [512,1024) = 2560
// ---------------------------------------------------------------------------
__global__ __launch_bounds__(256) void launch2(
    const bf16_t* __restrict__ h1_bf, const bf16_t* __restrict__ Aw2T,
    const float* __restrict__ Ab2, uint8_t* __restrict__ h2F,
    const bf16_t* __restrict__ h_bf, const float* __restrict__ Hw2,
    const float* __restrict__ Hb2, bf16_t* __restrict__ w_bf,
    const float* __restrict__ Aw3, uint8_t* __restrict__ Aw3T8F) {
  __shared__ __align__(16) char smem[SMEM_G64];
  const int b = blockIdx.x;
  if (b < 1024) {
    gemm64_body<4>(smem, b % 64, b / 64, h1_bf, 512, Aw2T, 512, 512, Ab2,
                   h2F, 0);
  } else if (b < 2048) {
    const int row = (b - 1024) * 4 + (threadIdx.x >> 6);
    hgrad_row(row, h_bf, Hw2, Hb2, w_bf);
  } else {
    aw3t_body(smem, Aw3, Aw3T8F, 512 + (b - 2048));  // tiles 512..1023
  }
}

// ---------------------------------------------------------------------------
// L3 (512 threads): Hbwd 64^2 8-wave (256) + A3 no-LDS (1024) = 1280.
// A3 swizzle: hardware XCD = p%8; each XCD owns a contiguous 8-wide by range
// (B working set 8 x 256KB = 2MB -> L2-resident), bx varies slowest.
// ---------------------------------------------------------------------------
__global__ __launch_bounds__(512, 2) void launch3(
    const bf16_t* __restrict__ w_bf, const bf16_t* __restrict__ Hw1_bf,
    float* __restrict__ out, const uint8_t* __restrict__ h2F,
    const uint8_t* __restrict__ Aw3T8F, const float* __restrict__ Ab3,
    const float* __restrict__ uvec) {
  __shared__ __align__(16) char smem[SMEM3_BYTES];
  const int b = blockIdx.x;
  if (b < 256) {
    hbwd64_body(smem, b % 64, b / 64, w_bf, 640, Hw1_bf, 640, 640, out, 256);
  } else {
    const int p = b - 256;                         // 0..1023; hw XCD = p % 8
    const int by = (p & 7) * 8 + ((p >> 3) & 7);   // 0..63
    const int bx = p >> 6;                         // 0..15
    a3_body(bx, by, h2F, Aw3T8F, out, Ab3, uvec);
  }
}

// ---------------------------------------------------------------------------
extern "C" void kernel_launch(void* const* d_in, const int* in_sizes, int n_in,
                              void* d_out, int out_size, void* d_ws,
                              size_t ws_size, hipStream_t stream) {
  (void)in_sizes; (void)n_in; (void)out_size; (void)ws_size;
  const float* inp = (const float*)d_in[1];
  const float* Hw1 = (const float*)d_in[2];
  const float* Hb1 = (const float*)d_in[3];
  const float* Hw2 = (const float*)d_in[4];
  const float* Hb2 = (const float*)d_in[5];
  const float* Aw1 = (const float*)d_in[6];
  const float* Ab1 = (const float*)d_in[7];
  const float* Aw2 = (const float*)d_in[8];
  const float* Ab2 = (const float*)d_in[9];
  const float* Aw3 = (const float*)d_in[10];
  const float* Ab3 = (const float*)d_in[11];
  const float* u = (const float*)d_in[12];
  float* out = (float*)d_out;

  char* ws = (char*)d_ws;
  bf16_t* inp_bf = (bf16_t*)ws;    ws += (size_t)NROW * 256 * 2;
  bf16_t* Hw1_bf = (bf16_t*)ws;    ws += (size_t)256 * 640 * 2;
  bf16_t* Hw1T = (bf16_t*)ws;      ws += (size_t)640 * 256 * 2;
  bf16_t* Aw1T = (bf16_t*)ws;      ws += (size_t)512 * 128 * 2;
  bf16_t* Aw2T = (bf16_t*)ws;      ws += (size_t)1024 * 512 * 2;
  uint8_t* Aw3T8F = (uint8_t*)ws;  ws += (size_t)16384 * 1024;
  bf16_t* h_bf = (bf16_t*)ws;      ws += (size_t)NROW * 640 * 2;
  bf16_t* w_bf = (bf16_t*)ws;      ws += (size_t)NROW * 640 * 2;
  bf16_t* h1_bf = (bf16_t*)ws;     ws += (size_t)NROW * 512 * 2;
  uint8_t* h2F = (uint8_t*)ws;     ws += (size_t)NROW * 1024;

  launch0<<<2944, 256, 0, stream>>>(inp, inp_bf, Hw1, Hw1T, Hw1_bf, Aw1, Aw1T,
                                    Aw2, Aw2T, out);
  launch1<<<1664, 256, 0, stream>>>(inp_bf, Hw1T, Hb1, h_bf, Aw1T, Ab1, h1_bf,
                                    Aw3, Aw3T8F);
  launch2<<<2560, 256, 0, stream>>>(h1_bf, Aw2T, Ab2, h2F, h_bf, Hw2, Hb2,
                                    w_bf, Aw3, Aw3T8F);
  launch3<<<1280, 512, 0, stream>>>(w_bf, Hw1_bf, out, h2F, Aw3T8F, Ab3, u);
}

// Round 8
// 366.432 us; speedup vs baseline: 1.0028x; 1.0028x over previous
//
#include <hip/hip_runtime.h>
#include <hip/hip_bf16.h>
#include <cstdint>

// ---------------------------------------------------------------------------
// Hamilton_V5  R17 = R16 resubmit (previous bench died to an infra error
// with zero kernel signal; kernel delta vs R15 is ONE attribute):
//  - launch3: __attribute__((amdgpu_waves_per_eu(2, 2))).
//    R15's allocator chose 128 VGPRs (4 waves/EU) and spilled ~120 regs
//    (WRITE_SIZE 20->390 MB, MfmaUtil 12%). Pinning min=max=2 waves/EU
//    gives the full 256-VGPR budget; a3 needs ~246.
//  - Everything else byte-identical to R15 (fragment-direct A3, no LDS /
//    no barriers in the K-loop; producers emit fragment-major layouts).
// ---------------------------------------------------------------------------

typedef __bf16 bf16_t;
typedef __bf16 bf16x4_t __attribute__((ext_vector_type(4)));
typedef __bf16 bf16x8_t __attribute__((ext_vector_type(8)));
typedef float f32x4_t __attribute__((ext_vector_type(4)));
typedef float f32x16_t __attribute__((ext_vector_type(16)));
typedef int intx4_t __attribute__((ext_vector_type(4)));
typedef int intx8_t __attribute__((ext_vector_type(8)));

#define DIMD 128
#define NROW 4096
#define SMEM_G64 24576     // gemm64 3-buf (3*4096*2) ; aw3t 16896 fits
#define SMEM3_BYTES 24576  // hbwd 3-buf only; a3 uses no LDS

// branchless tanh: t=2^(2x*log2e); tanh=1-2/(t+1).
__device__ __forceinline__ float fast_tanh(float x) {
  float t = __builtin_amdgcn_exp2f(x * 2.8853900817779268f);
  return 1.f - 2.f * __builtin_amdgcn_rcpf(t + 1.f);
}

// f32 -> fp8 e4m3 (OCP), RNE+sat via HW cvt
__device__ __forceinline__ uint8_t to_fp8(float x) {
  return (uint8_t)(__builtin_amdgcn_cvt_pk_fp8_f32(x, x, 0, false) & 0xff);
}

// pack 4 f32 -> 4 fp8 bytes (byte0=a .. byte3=d) via 2 HW cvt_pk
__device__ __forceinline__ uint32_t pk4_fp8(float a, float b, float c,
                                            float d) {
  uint32_t lo = (uint32_t)__builtin_amdgcn_cvt_pk_fp8_f32(a, b, 0, false);
  return (uint32_t)__builtin_amdgcn_cvt_pk_fp8_f32(c, d, lo, true);
}

// async global->LDS, 16B per lane; LDS dest = wave-uniform base + lane*16
__device__ __forceinline__ void g2l16(const void* gp, void* lp) {
  __builtin_amdgcn_global_load_lds(
      reinterpret_cast<__attribute__((address_space(1))) void*>(
          reinterpret_cast<uintptr_t>(gp)),
      reinterpret_cast<__attribute__((address_space(3))) void*>(
          reinterpret_cast<uintptr_t>(lp)),
      16, 0, 0);
}

// DPP accumulating add (VALU pipe -- no LDS). bound_ctrl=1 => 0-fill.
template <int CTRL>
__device__ __forceinline__ float dpp_addf(float v) {
  return v + __int_as_float(__builtin_amdgcn_update_dpp(
                 0, __float_as_int(v), CTRL, 0xf, 0xf, true));
}
// sum over each 32-lane half; result in lane 31 (half 0) / lane 63 (half 1).
__device__ __forceinline__ float dpp_sum32(float v) {
  v = dpp_addf<0x111>(v);  // row_shr:1
  v = dpp_addf<0x112>(v);  // row_shr:2
  v = dpp_addf<0x114>(v);  // row_shr:4
  v = dpp_addf<0x118>(v);  // row_shr:8  -> lane15/31/47/63 = row sums
  v = dpp_addf<0x142>(v);  // row_bcast15 -> lane31/63 = 32-lane sums
  return v;
}

// ---------------------------------------------------------------------------
// bf16 GEMM, 64x64 tile, BK=32, 4 waves 2x2 (each 32x32 = 2x2 mfma 16x16x32).
// Triple-buffered LDS, depth-2 prefetch, counted vmcnt(2) per step.
// EPI 0: bf16 tanh(C+b); EPI 4: fp8 x64 fragment-major (h2F).
// ---------------------------------------------------------------------------
template <int EPI>
__device__ __forceinline__ void gemm64_body(char* smem, int bx, int by,
                                            const bf16_t* A, int lda,
                                            const bf16_t* B, int ldb, int K,
                                            const float* bias, void* outp,
                                            int ldo) {
  constexpr int BK = 32;
  bf16_t* As = (bf16_t*)smem;   // 3 x 64*32
  bf16_t* Bs = As + 3 * 2048;   // 3 x 64*32
  const int NT = K / BK;

  const int m0 = bx * 64;
  const int n0 = by * 64;
  const int tid = threadIdx.x;
  const int wave = tid >> 6;
  const int lane = tid & 63;
  const int wm = wave >> 1;
  const int wn = wave & 1;

  const int sr = lane >> 2;
  const int sk = (((lane & 3) ^ ((sr >> 1) & 3)) * 8);
  const int fr = lane & 15;
  const int fk = (((lane >> 4) ^ ((fr >> 1) & 3)) * 8);
  const int rb = wave * 16;  // each wave stages 16 rows of A and B

  const bf16_t* Ag = A + (size_t)(m0 + rb + sr) * lda + sk;
  const bf16_t* Bg = B + (size_t)(n0 + rb + sr) * ldb + sk;

#define G64_STAGE(buf, k0)                              \
  do {                                                  \
    g2l16(Ag + (k0), As + (buf) * 2048 + rb * BK);      \
    g2l16(Bg + (k0), Bs + (buf) * 2048 + rb * BK);      \
  } while (0)

  f32x4_t acc[2][2] = {};

  G64_STAGE(0, 0);
  G64_STAGE(1, BK);
  asm volatile("s_waitcnt vmcnt(2)" ::: "memory");
  __builtin_amdgcn_s_barrier();
  asm volatile("" ::: "memory");

  for (int t = 0; t < NT; ++t) {
    if (t + 2 < NT) G64_STAGE((t + 2) % 3, (t + 2) * BK);
    const bf16_t* Ab = As + (t % 3) * 2048;
    const bf16_t* Bb = Bs + (t % 3) * 2048;

    bf16x8_t af[2], bb[2];
#pragma unroll
    for (int u = 0; u < 2; ++u) {
      af[u] = *(const bf16x8_t*)(Ab + (wm * 32 + u * 16 + fr) * BK + fk);
      bb[u] = *(const bf16x8_t*)(Bb + (wn * 32 + u * 16 + fr) * BK + fk);
    }
#pragma unroll
    for (int i = 0; i < 2; ++i)
#pragma unroll
      for (int j = 0; j < 2; ++j)
        acc[i][j] = __builtin_amdgcn_mfma_f32_16x16x32_bf16(af[i], bb[j],
                                                            acc[i][j], 0, 0, 0);
    if (t < NT - 1) {
      if (t + 2 < NT)
        asm volatile("s_waitcnt vmcnt(2)" ::: "memory");
      else
        asm volatile("s_waitcnt vmcnt(0)" ::: "memory");
      __builtin_amdgcn_s_barrier();
      asm volatile("" ::: "memory");
    }
  }
#undef G64_STAGE

  // C/D layout (m89): col = lane&15, row = (lane>>4)*4 + reg
#pragma unroll
  for (int i = 0; i < 2; ++i) {
    const int row = m0 + wm * 32 + i * 16 + (lane >> 4) * 4;
#pragma unroll
    for (int j = 0; j < 2; ++j) {
      const int col = n0 + wn * 32 + j * 16 + fr;
      if constexpr (EPI == 0) {
        bf16_t* O = (bf16_t*)outp;
        const float b = bias[col];
#pragma unroll
        for (int r = 0; r < 4; ++r)
          O[(size_t)(row + r) * ldo + col] = (bf16_t)fast_tanh(acc[i][j][r] + b);
      } else {  // EPI 4: h2 fragment-major fp8
        uint8_t* O = (uint8_t*)outp;
        const float b = bias[col];
        const int kb = col >> 6;
        const int khalf = (col >> 5) & 1;
        const int kin = col & 31;
#pragma unroll
        for (int r = 0; r < 4; ++r) {
          const int rw = row + r;
          O[(size_t)((rw >> 5) * 16 + kb) * 2048 +
            (khalf * 32 + (rw & 31)) * 32 + kin] =
              to_fp8(64.f * fast_tanh(acc[i][j][r] + b));
        }
      }
    }
  }
}

// ---------------------------------------------------------------------------
// Hbwd bf16 GEMM for 512-thread launch: 64x64 tile, BK=32, 8 waves arranged
// 2x4; per-wave 32x16 = 2x1 mfma 16x16x32.  dx store / dv atomicAdd(-C).
// Triple-buffer/counted-vmcnt pipeline (1 stage op per wave).
// ---------------------------------------------------------------------------
__device__ __forceinline__ void hbwd64_body(char* smem, int bx, int by,
                                            const bf16_t* A, int lda,
                                            const bf16_t* B, int ldb, int K,
                                            float* out, int ldo) {
  constexpr int BK = 32;
  bf16_t* As = (bf16_t*)smem;  // 3 x 64*32
  bf16_t* Bs = As + 3 * 2048;
  const int NT = K / BK;  // 20

  const int m0 = bx * 64;
  const int n0 = by * 64;
  const int tid = threadIdx.x;
  const int wave = tid >> 6;  // 0..7
  const int lane = tid & 63;
  const int wm = wave >> 2;   // 0..1
  const int wn = wave & 3;    // 0..3

  const int sr = lane >> 2;
  const int sk = (((lane & 3) ^ ((sr >> 1) & 3)) * 8);
  const int fr = lane & 15;
  const int fk = (((lane >> 4) ^ ((fr >> 1) & 3)) * 8);

  // waves 0..3 stage A rows, 4..7 stage B rows (1 g2l16 per wave per step)
  const int rbs = (wave & 3) * 16;
  const bf16_t* Sg = (wave < 4) ? A + (size_t)(m0 + rbs + sr) * lda + sk
                                : B + (size_t)(n0 + rbs + sr) * ldb + sk;
  bf16_t* Sl = ((wave < 4) ? As : Bs) + rbs * BK;

  f32x4_t acc[2] = {};

  g2l16(Sg, Sl);
  g2l16(Sg + BK, Sl + 2048);
  asm volatile("s_waitcnt vmcnt(1)" ::: "memory");
  __builtin_amdgcn_s_barrier();
  asm volatile("" ::: "memory");

  for (int t = 0; t < NT; ++t) {
    if (t + 2 < NT) g2l16(Sg + (t + 2) * BK, Sl + ((t + 2) % 3) * 2048);
    const bf16_t* Ab = As + (t % 3) * 2048;
    const bf16_t* Bb = Bs + (t % 3) * 2048;

    const bf16x8_t bb = *(const bf16x8_t*)(Bb + (wn * 16 + fr) * BK + fk);
#pragma unroll
    for (int u = 0; u < 2; ++u) {
      const bf16x8_t af =
          *(const bf16x8_t*)(Ab + (wm * 32 + u * 16 + fr) * BK + fk);
      acc[u] = __builtin_amdgcn_mfma_f32_16x16x32_bf16(af, bb, acc[u], 0, 0, 0);
    }
    if (t < NT - 1) {
      if (t + 2 < NT)
        asm volatile("s_waitcnt vmcnt(1)" ::: "memory");
      else
        asm volatile("s_waitcnt vmcnt(0)" ::: "memory");
      __builtin_amdgcn_s_barrier();
      asm volatile("" ::: "memory");
    }
  }

  // C/D layout (m89): col = lane&15, row = (lane>>4)*4 + reg
  const bool dx = (n0 < DIMD);
  const int col = n0 + wn * 16 + fr;
#pragma unroll
  for (int t = 0; t < 2; ++t) {
    const int row = m0 + wm * 32 + t * 16 + (lane >> 4) * 4;
#pragma unroll
    for (int r = 0; r < 4; ++r) {
      const size_t idx = (size_t)(row + r) * ldo + col;
      if (dx) out[idx] = acc[t][r];
      else atomicAdd(&out[idx], -acc[t][r]);  // dv_H shares with dvA
    }
  }
}

// ---------------------------------------------------------------------------
// A3 fused GEMM, MX-fp8: 512 threads / 8 waves, BM=256, BN=256, BK=64.
// Wave grid 4x2: each wave 64x128 via 2x4 mfma 32x32x64 (acc[2][4] f32x16).
// NO LDS, NO BARRIERS: operands loaded L2->reg as pre-swizzled fragments
// (AF = h2F 4MB, BF = Aw3T8F 16MB).  Even/odd double-buffered loads;
// compiler auto-vmcnt via data dependence.
// ---------------------------------------------------------------------------
__device__ __forceinline__ void a3_body(int bx, int by, const uint8_t* AF,
                                        const uint8_t* BF, float* out,
                                        const float* ab3, const float* uvec) {
  constexpr int NT = 16;  // K / 64
  const int tid = threadIdx.x;
  const int wave = tid >> 6;  // 0..7
  const int lane = tid & 63;
  const int wm = wave >> 1;   // 0..3 : 64-row strip
  const int wn = wave & 1;    // 0..1 : 128-col strip
  const int rl = lane & 31;
  const int m0 = bx * 256;
  const int n0 = by * 256;

  // fragment stream base pointers (lane's 32B slice of each 2KB chunk)
  const uint8_t* bp[6];
#pragma unroll
  for (int i = 0; i < 2; ++i)
    bp[i] = AF + (size_t)(bx * 8 + wm * 2 + i) * 16 * 2048 + lane * 32;
#pragma unroll
  for (int j = 0; j < 4; ++j)
    bp[2 + j] = BF + (size_t)(by * 8 + wn * 4 + j) * 16 * 2048 + lane * 32;

  f32x16_t acc[2][4] = {};
  intx4_t cur[12], nxt[12];

#define A3_LOADSET(dst, off)                                   \
  _Pragma("unroll") for (int q = 0; q < 6; ++q) {              \
    dst[2 * q] = *(const intx4_t*)(bp[q] + (off));             \
    dst[2 * q + 1] = *(const intx4_t*)(bp[q] + (off) + 16);    \
  }

#define A3_MFMASET(S)                                                         \
  _Pragma("unroll") for (int i = 0; i < 2; ++i) {                             \
    intx8_t af = __builtin_shufflevector(S[2 * i], S[2 * i + 1], 0, 1, 2, 3,  \
                                         4, 5, 6, 7);                         \
    _Pragma("unroll") for (int j = 0; j < 4; ++j) {                           \
      intx8_t bf = __builtin_shufflevector(S[4 + 2 * j], S[5 + 2 * j], 0, 1,  \
                                           2, 3, 4, 5, 6, 7);                 \
      acc[i][j] = __builtin_amdgcn_mfma_scale_f32_32x32x64_f8f6f4(            \
          af, bf, acc[i][j], 0, 0, 0, 0x79797979, 0, 0x79797979);             \
    }                                                                         \
  }

  A3_LOADSET(cur, 0);
#pragma unroll 1
  for (int t = 0; t < NT; t += 2) {
    A3_LOADSET(nxt, (size_t)(t + 1) * 2048);
    A3_MFMASET(cur);
    if (t + 2 < NT) A3_LOADSET(cur, (size_t)(t + 2) * 2048);
    A3_MFMASET(nxt);
  }
#undef A3_LOADSET
#undef A3_MFMASET

  // epilogue: C/D col = lane&31, row = (reg&3)+8*(reg>>2)+4*(lane>>5).
  // wave's 128 cols are one full u-period -> ONE out column 128+2by+wn.
  const int q = lane >> 5;
  float uu[4], b3[4];
#pragma unroll
  for (int j = 0; j < 4; ++j) {
    uu[j] = uvec[j * 32 + rl];
    b3[j] = ab3[n0 + wn * 128 + j * 32 + rl];
  }
  const int ocol = 128 + 2 * by + wn;
#pragma unroll
  for (int i = 0; i < 2; ++i) {
    float s16[16];
#pragma unroll
    for (int r = 0; r < 16; ++r) {
      float s = 0.f;
#pragma unroll
      for (int j = 0; j < 4; ++j) s += fast_tanh(acc[i][j][r] + b3[j]) * uu[j];
      s16[r] = s;
    }
#pragma unroll
    for (int r = 0; r < 16; ++r) s16[r] = dpp_sum32(s16[r]);
    if (rl == 31) {  // lanes 31 and 63 hold the two q-half sums
      const int rowb = m0 + wm * 64 + i * 32 + 4 * q;
#pragma unroll
      for (int r = 0; r < 16; ++r)
        atomicAdd(&out[(size_t)(rowb + (r & 3) + 8 * (r >> 2)) * 256 + ocol],
                  s16[r]);
    }
  }
}

// ---------------------------------------------------------------------------
// transposes / cvt helpers
// ---------------------------------------------------------------------------
__device__ __forceinline__ void tcvt_body(char* smem, const float* in,
                                          bf16_t* out, int R, int C, int bx,
                                          int by) {
  float(*t)[33] = (float(*)[33])smem;  // 4224 B
  const int c0 = bx * 32;
  const int r0 = by * 32;
  const int tx = threadIdx.x & 31;
  const int ty = threadIdx.x >> 5;
#pragma unroll
  for (int k = 0; k < 4; ++k)
    t[ty + k * 8][tx] = in[(size_t)(r0 + ty + k * 8) * C + c0 + tx];
  __syncthreads();
#pragma unroll
  for (int k = 0; k < 4; ++k)
    out[(size_t)(c0 + ty + k * 8) * R + r0 + tx] = (bf16_t)t[tx][ty + k * 8];
}

// Aw3 (1024 x 16384) -> fp8 x64, FRAGMENT-MAJOR (Aw3T8F).
// 128x128 tile per block (1024 blocks), float4 reads, cvt_pk packing,
// u32-transposed LDS [128][33]; drain writes fragment chunks:
//   chunk ((cb*16)+kb)*2048, byte (khalf*32 + col%32)*32 + k%32.
__device__ __forceinline__ void aw3t_body(char* smem, const float* Aw3,
                                          uint8_t* Aw3T8F, int b) {
  uint32_t(*T)[33] = (uint32_t(*)[33])smem;  // 16896 B
  const int ct = b & 127;
  const int rt = b >> 7;
  const size_t c0 = (size_t)ct * 128;
  const int r0 = rt * 128;
  const int tx = threadIdx.x & 31;  // col-chunk (4 f32)
  const int g = threadIdx.x >> 5;   // 0..7 row-group
#pragma unroll
  for (int k = 0; k < 4; ++k) {
    const int rr = r0 + 4 * g + 32 * k;
    const float4 v0 = *(const float4*)(Aw3 + (size_t)(rr + 0) * 16384 + c0 + 4 * tx);
    const float4 v1 = *(const float4*)(Aw3 + (size_t)(rr + 1) * 16384 + c0 + 4 * tx);
    const float4 v2 = *(const float4*)(Aw3 + (size_t)(rr + 2) * 16384 + c0 + 4 * tx);
    const float4 v3 = *(const float4*)(Aw3 + (size_t)(rr + 3) * 16384 + c0 + 4 * tx);
    const int r4 = g + 8 * k;  // row/4 within tile (k-dim of output)
    T[4 * tx + 0][r4] = pk4_fp8(64.f * v0.x, 64.f * v1.x, 64.f * v2.x, 64.f * v3.x);
    T[4 * tx + 1][r4] = pk4_fp8(64.f * v0.y, 64.f * v1.y, 64.f * v2.y, 64.f * v3.y);
    T[4 * tx + 2][r4] = pk4_fp8(64.f * v0.z, 64.f * v1.z, 64.f * v2.z, 64.f * v3.z);
    T[4 * tx + 3][r4] = pk4_fp8(64.f * v0.w, 64.f * v1.w, 64.f * v2.w, 64.f * v3.w);
  }
  __syncthreads();
  // T[cc][tx] = 4 fp8 bytes: col = c0+cc, k = r0+4*tx .. +3
  const int kb = (rt << 1) + (tx >> 4);     // k-block (64)
  const int khalf = (tx >> 3) & 1;          // k-half (32)
  const int kin = (tx & 7) << 2;            // k%32 (4-aligned)
#pragma unroll
  for (int k2 = 0; k2 < 16; ++k2) {
    const int cc = g + 8 * k2;
    const int cb = (ct << 2) + (cc >> 5);
    const int cin = cc & 31;
    *(uint32_t*)(Aw3T8F + (size_t)(cb * 16 + kb) * 2048 +
                 (khalf * 32 + cin) * 32 + kin) = T[cc][tx];
  }
}

// one wave handles one row: pre2 = h.Hw2; w_j = s*Hw2_j*(1-h_j^2)
__device__ __forceinline__ void hgrad_row(int row, const bf16_t* h,
                                          const float* Hw2, const float* Hb2,
                                          bf16_t* wout) {
  const int lane = threadIdx.x & 63;
  float hv[10], wv[10];
  float pre2 = 0.f;
#pragma unroll
  for (int t = 0; t < 10; ++t) {
    const int j = lane + t * 64;
    hv[t] = (float)h[(size_t)row * 640 + j];
    wv[t] = Hw2[j];
    pre2 += hv[t] * wv[t];
  }
#pragma unroll
  for (int d = 1; d < 64; d <<= 1) pre2 += __shfl_xor(pre2, d, 64);
  const float y = fast_tanh(pre2 + Hb2[0]);
  const float s = 1.f - y * y;
#pragma unroll
  for (int t = 0; t < 10; ++t) {
    const int j = lane + t * 64;
    wout[(size_t)row * 640 + j] = (bf16_t)(s * wv[t] * (1.f - hv[t] * hv[t]));
  }
}

// ---------------------------------------------------------------------------
// L0: inp cvt (1024) + Hw1T (160) + Aw1T (64) + Aw2T (512) + Hw1_bf cvt (160)
//     + zero-out (1024) = 2944 blocks
// ---------------------------------------------------------------------------
__global__ __launch_bounds__(256) void launch0(
    const float* __restrict__ inp, bf16_t* __restrict__ inp_bf,
    const float* __restrict__ Hw1, bf16_t* __restrict__ Hw1T,
    bf16_t* __restrict__ Hw1_bf, const float* __restrict__ Aw1,
    bf16_t* __restrict__ Aw1T, const float* __restrict__ Aw2,
    bf16_t* __restrict__ Aw2T, float* __restrict__ out) {
  __shared__ __align__(16) char smem[4224];
  int b = blockIdx.x;
  if (b < 1024) {
    const int i = b * 256 + threadIdx.x;
    const float4 v = ((const float4*)inp)[i];
    bf16x4_t o = {(bf16_t)v.x, (bf16_t)v.y, (bf16_t)v.z, (bf16_t)v.w};
    ((bf16x4_t*)inp_bf)[i] = o;
  } else if (b < 1184) {
    int s = b - 1024;
    tcvt_body(smem, Hw1, Hw1T, 256, 640, s % 20, s / 20);
  } else if (b < 1248) {
    int s = b - 1184;
    tcvt_body(smem, Aw1, Aw1T, 128, 512, s % 16, s / 16);
  } else if (b < 1760) {
    int s = b - 1248;
    tcvt_body(smem, Aw2, Aw2T, 512, 1024, s % 32, s / 32);
  } else if (b < 1920) {
    const int i = (b - 1760) * 256 + threadIdx.x;
    const float4 v = ((const float4*)Hw1)[i];
    bf16x4_t o = {(bf16_t)v.x, (bf16_t)v.y, (bf16_t)v.z, (bf16_t)v.w};
    ((bf16x4_t*)Hw1_bf)[i] = o;
  } else {
    const int i = (b - 1920) * 256 + threadIdx.x;
    ((float4*)out)[i] = make_float4(0.f, 0.f, 0.f, 0.f);
  }
}

// ---------------------------------------------------------------------------
// L1: Hfwd 64^2 (640) + A1 64^2 (512) + Aw3T tiles [0,512) = 1664 blocks
// ---------------------------------------------------------------------------
__global__ __launch_bounds__(256) void launch1(
    const bf16_t* __restrict__ inp_bf, const bf16_t* __restrict__ Hw1T,
    const float* __restrict__ Hb1, bf16_t* __restrict__ h_bf,
    const bf16_t* __restrict__ Aw1T, const float* __restrict__ Ab1,
    bf16_t* __restrict__ h1_bf, const float* __restrict__ Aw3,
    uint8_t* __restrict__ Aw3T8F) {
  __shared__ __align__(16) char smem[SMEM_G64];
  const int b = blockIdx.x;
  if (b < 640) {
    gemm64_body<0>(smem, b % 64, b / 64, inp_bf, 256, Hw1T, 256, 256, Hb1,
                   h_bf, 640);
  } else if (b < 1152) {
    const int i = b - 640;
    gemm64_body<0>(smem, i % 64, i / 64, inp_bf, 256, Aw1T, 128, 128, Ab1,
                   h1_bf, 512);
  } else {
    aw3t_body(smem, Aw3, Aw3T8F, b - 1152);  // tiles 0..511
  }
}

// ---------------------------------------------------------------------------
// L2: A2->h2F 64^2 (1024) + hgrad (1024) + Aw3T tiles [512,1024) = 2560
// ---------------------------------------------------------------------------
__global__ __launch_bounds__(256) void launch2(
    const bf16_t* __restrict__ h1_bf, const bf16_t* __restrict__ Aw2T,
    const float* __restrict__ Ab2, uint8_t* __restrict__ h2F,
    const bf16_t* __restrict__ h_bf, const float* __restrict__ Hw2,
    const float* __restrict__ Hb2, bf16_t* __restrict__ w_bf,
    const float* __restrict__ Aw3, uint8_t* __restrict__ Aw3T8F) {
  __shared__ __align__(16) char smem[SMEM_G64];
  const int b = blockIdx.x;
  if (b < 1024) {
    gemm64_body<4>(smem, b % 64, b / 64, h1_bf, 512, Aw2T, 512, 512, Ab2,
                   h2F, 0);
  } else if (b < 2048) {
    const int row = (b - 1024) * 4 + (threadIdx.x >> 6);
    hgrad_row(row, h_bf, Hw2, Hb2, w_bf);
  } else {
    aw3t_body(smem, Aw3, Aw3T8F, 512 + (b - 2048));  // tiles 512..1023
  }
}

// ---------------------------------------------------------------------------
// L3 (512 threads): Hbwd 64^2 8-wave (256) + A3 no-LDS (1024) = 1280.
// amdgpu_waves_per_eu(2,2): pin exactly 2 waves/EU so the allocator gets
// the full 256-VGPR budget (R15: it chose 128 + spill -> 2.5x regression).
// A3 swizzle: hardware XCD = p%8; each XCD owns a contiguous 8-wide by range
// (B working set 8 x 256KB = 2MB -> L2-resident), bx varies slowest.
// ---------------------------------------------------------------------------
__global__ __launch_bounds__(512)
__attribute__((amdgpu_waves_per_eu(2, 2))) void launch3(
    const bf16_t* __restrict__ w_bf, const bf16_t* __restrict__ Hw1_bf,
    float* __restrict__ out, const uint8_t* __restrict__ h2F,
    const uint8_t* __restrict__ Aw3T8F, const float* __restrict__ Ab3,
    const float* __restrict__ uvec) {
  __shared__ __align__(16) char smem[SMEM3_BYTES];
  const int b = blockIdx.x;
  if (b < 256) {
    hbwd64_body(smem, b % 64, b / 64, w_bf, 640, Hw1_bf, 640, 640, out, 256);
  } else {
    const int p = b - 256;                         // 0..1023; hw XCD = p % 8
    const int by = (p & 7) * 8 + ((p >> 3) & 7);   // 0..63
    const int bx = p >> 6;                         // 0..15
    a3_body(bx, by, h2F, Aw3T8F, out, Ab3, uvec);
  }
}

// ---------------------------------------------------------------------------
extern "C" void kernel_launch(void* const* d_in, const int* in_sizes, int n_in,
                              void* d_out, int out_size, void* d_ws,
                              size_t ws_size, hipStream_t stream) {
  (void)in_sizes; (void)n_in; (void)out_size; (void)ws_size;
  const float* inp = (const float*)d_in[1];
  const float* Hw1 = (const float*)d_in[2];
  const float* Hb1 = (const float*)d_in[3];
  const float* Hw2 = (const float*)d_in[4];
  const float* Hb2 = (const float*)d_in[5];
  const float* Aw1 = (const float*)d_in[6];
  const float* Ab1 = (const float*)d_in[7];
  const float* Aw2 = (const float*)d_in[8];
  const float* Ab2 = (const float*)d_in[9];
  const float* Aw3 = (const float*)d_in[10];
  const float* Ab3 = (const float*)d_in[11];
  const float* u = (const float*)d_in[12];
  float* out = (float*)d_out;

  char* ws = (char*)d_ws;
  bf16_t* inp_bf = (bf16_t*)ws;    ws += (size_t)NROW * 256 * 2;
  bf16_t* Hw1_bf = (bf16_t*)ws;    ws += (size_t)256 * 640 * 2;
  bf16_t* Hw1T = (bf16_t*)ws;      ws += (size_t)640 * 256 * 2;
  bf16_t* Aw1T = (bf16_t*)ws;      ws += (size_t)512 * 128 * 2;
  bf16_t* Aw2T = (bf16_t*)ws;      ws += (size_t)1024 * 512 * 2;
  uint8_t* Aw3T8F = (uint8_t*)ws;  ws += (size_t)16384 * 1024;
  bf16_t* h_bf = (bf16_t*)ws;      ws += (size_t)NROW * 640 * 2;
  bf16_t* w_bf = (bf16_t*)ws;      ws += (size_t)NROW * 640 * 2;
  bf16_t* h1_bf = (bf16_t*)ws;     ws += (size_t)NROW * 512 * 2;
  uint8_t* h2F = (uint8_t*)ws;     ws += (size_t)NROW * 1024;

  launch0<<<2944, 256, 0, stream>>>(inp, inp_bf, Hw1, Hw1T, Hw1_bf, Aw1, Aw1T,
                                    Aw2, Aw2T, out);
  launch1<<<1664, 256, 0, stream>>>(inp_bf, Hw1T, Hb1, h_bf, Aw1T, Ab1, h1_bf,
                                    Aw3, Aw3T8F);
  launch2<<<2560, 256, 0, stream>>>(h1_bf, Aw2T, Ab2, h2F, h_bf, Hw2, Hb2,
                                    w_bf, Aw3, Aw3T8F);
  launch3<<<1280, 512, 0, stream>>>(w_bf, Hw1_bf, out, h2F, Aw3T8F, Ab3, u);
}

// Round 9
// 254.557 us; speedup vs baseline: 1.4436x; 1.4395x over previous
//
#include <hip/hip_runtime.h>
#include <hip/hip_bf16.h>
#include <cstdint>

// ---------------------------------------------------------------------------
// Hamilton_V5  R18:
//  - A3 register-budget fix (R15/R17 spilled: acc 128 AGPR + ~160 arch >
//    256 unified budget -> 400MB scratch, MfmaUtil 12%).
//    Wave tile 64x128 -> 64x64: acc[2][2] = 64 AGPR; arch ~110
//    (cur[8]+nxt[8]+4 stream ptrs+misc); total ~174 <= R14's proven 228.
//  - Still fragment-direct: ZERO LDS / ZERO barriers in the A3 K-loop;
//    operands stream L2->reg as pre-swizzled MFMA fragments.
//    8 waves = 4(wm) x 2(wn); block 256x128; grid 16x128 = 2048 blocks.
//    BN=128 = one u-period -> out col = 128+by exactly.
//  - __launch_bounds__(512, 2) (R14's verified no-spill config);
//    amdgpu_waves_per_eu removed (did not bind, R17).
//  - Producers (h2F, Aw3T8F fragment-major) + L0/L1/L2 + hbwd unchanged.
// ---------------------------------------------------------------------------

typedef __bf16 bf16_t;
typedef __bf16 bf16x4_t __attribute__((ext_vector_type(4)));
typedef __bf16 bf16x8_t __attribute__((ext_vector_type(8)));
typedef float f32x4_t __attribute__((ext_vector_type(4)));
typedef float f32x16_t __attribute__((ext_vector_type(16)));
typedef int intx4_t __attribute__((ext_vector_type(4)));
typedef int intx8_t __attribute__((ext_vector_type(8)));

#define DIMD 128
#define NROW 4096
#define SMEM_G64 24576     // gemm64 3-buf (3*4096*2) ; aw3t 16896 fits
#define SMEM3_BYTES 24576  // hbwd 3-buf only; a3 uses no LDS

// branchless tanh: t=2^(2x*log2e); tanh=1-2/(t+1).
__device__ __forceinline__ float fast_tanh(float x) {
  float t = __builtin_amdgcn_exp2f(x * 2.8853900817779268f);
  return 1.f - 2.f * __builtin_amdgcn_rcpf(t + 1.f);
}

// f32 -> fp8 e4m3 (OCP), RNE+sat via HW cvt
__device__ __forceinline__ uint8_t to_fp8(float x) {
  return (uint8_t)(__builtin_amdgcn_cvt_pk_fp8_f32(x, x, 0, false) & 0xff);
}

// pack 4 f32 -> 4 fp8 bytes (byte0=a .. byte3=d) via 2 HW cvt_pk
__device__ __forceinline__ uint32_t pk4_fp8(float a, float b, float c,
                                            float d) {
  uint32_t lo = (uint32_t)__builtin_amdgcn_cvt_pk_fp8_f32(a, b, 0, false);
  return (uint32_t)__builtin_amdgcn_cvt_pk_fp8_f32(c, d, lo, true);
}

// async global->LDS, 16B per lane; LDS dest = wave-uniform base + lane*16
__device__ __forceinline__ void g2l16(const void* gp, void* lp) {
  __builtin_amdgcn_global_load_lds(
      reinterpret_cast<__attribute__((address_space(1))) void*>(
          reinterpret_cast<uintptr_t>(gp)),
      reinterpret_cast<__attribute__((address_space(3))) void*>(
          reinterpret_cast<uintptr_t>(lp)),
      16, 0, 0);
}

// DPP accumulating add (VALU pipe -- no LDS). bound_ctrl=1 => 0-fill.
template <int CTRL>
__device__ __forceinline__ float dpp_addf(float v) {
  return v + __int_as_float(__builtin_amdgcn_update_dpp(
                 0, __float_as_int(v), CTRL, 0xf, 0xf, true));
}
// sum over each 32-lane half; result in lane 31 (half 0) / lane 63 (half 1).
__device__ __forceinline__ float dpp_sum32(float v) {
  v = dpp_addf<0x111>(v);  // row_shr:1
  v = dpp_addf<0x112>(v);  // row_shr:2
  v = dpp_addf<0x114>(v);  // row_shr:4
  v = dpp_addf<0x118>(v);  // row_shr:8  -> lane15/31/47/63 = row sums
  v = dpp_addf<0x142>(v);  // row_bcast15 -> lane31/63 = 32-lane sums
  return v;
}

// ---------------------------------------------------------------------------
// bf16 GEMM, 64x64 tile, BK=32, 4 waves 2x2 (each 32x32 = 2x2 mfma 16x16x32).
// Triple-buffered LDS, depth-2 prefetch, counted vmcnt(2) per step.
// EPI 0: bf16 tanh(C+b); EPI 4: fp8 x64 fragment-major (h2F).
// ---------------------------------------------------------------------------
template <int EPI>
__device__ __forceinline__ void gemm64_body(char* smem, int bx, int by,
                                            const bf16_t* A, int lda,
                                            const bf16_t* B, int ldb, int K,
                                            const float* bias, void* outp,
                                            int ldo) {
  constexpr int BK = 32;
  bf16_t* As = (bf16_t*)smem;   // 3 x 64*32
  bf16_t* Bs = As + 3 * 2048;   // 3 x 64*32
  const int NT = K / BK;

  const int m0 = bx * 64;
  const int n0 = by * 64;
  const int tid = threadIdx.x;
  const int wave = tid >> 6;
  const int lane = tid & 63;
  const int wm = wave >> 1;
  const int wn = wave & 1;

  const int sr = lane >> 2;
  const int sk = (((lane & 3) ^ ((sr >> 1) & 3)) * 8);
  const int fr = lane & 15;
  const int fk = (((lane >> 4) ^ ((fr >> 1) & 3)) * 8);
  const int rb = wave * 16;  // each wave stages 16 rows of A and B

  const bf16_t* Ag = A + (size_t)(m0 + rb + sr) * lda + sk;
  const bf16_t* Bg = B + (size_t)(n0 + rb + sr) * ldb + sk;

#define G64_STAGE(buf, k0)                              \
  do {                                                  \
    g2l16(Ag + (k0), As + (buf) * 2048 + rb * BK);      \
    g2l16(Bg + (k0), Bs + (buf) * 2048 + rb * BK);      \
  } while (0)

  f32x4_t acc[2][2] = {};

  G64_STAGE(0, 0);
  G64_STAGE(1, BK);
  asm volatile("s_waitcnt vmcnt(2)" ::: "memory");
  __builtin_amdgcn_s_barrier();
  asm volatile("" ::: "memory");

  for (int t = 0; t < NT; ++t) {
    if (t + 2 < NT) G64_STAGE((t + 2) % 3, (t + 2) * BK);
    const bf16_t* Ab = As + (t % 3) * 2048;
    const bf16_t* Bb = Bs + (t % 3) * 2048;

    bf16x8_t af[2], bb[2];
#pragma unroll
    for (int u = 0; u < 2; ++u) {
      af[u] = *(const bf16x8_t*)(Ab + (wm * 32 + u * 16 + fr) * BK + fk);
      bb[u] = *(const bf16x8_t*)(Bb + (wn * 32 + u * 16 + fr) * BK + fk);
    }
#pragma unroll
    for (int i = 0; i < 2; ++i)
#pragma unroll
      for (int j = 0; j < 2; ++j)
        acc[i][j] = __builtin_amdgcn_mfma_f32_16x16x32_bf16(af[i], bb[j],
                                                            acc[i][j], 0, 0, 0);
    if (t < NT - 1) {
      if (t + 2 < NT)
        asm volatile("s_waitcnt vmcnt(2)" ::: "memory");
      else
        asm volatile("s_waitcnt vmcnt(0)" ::: "memory");
      __builtin_amdgcn_s_barrier();
      asm volatile("" ::: "memory");
    }
  }
#undef G64_STAGE

  // C/D layout (m89): col = lane&15, row = (lane>>4)*4 + reg
#pragma unroll
  for (int i = 0; i < 2; ++i) {
    const int row = m0 + wm * 32 + i * 16 + (lane >> 4) * 4;
#pragma unroll
    for (int j = 0; j < 2; ++j) {
      const int col = n0 + wn * 32 + j * 16 + fr;
      if constexpr (EPI == 0) {
        bf16_t* O = (bf16_t*)outp;
        const float b = bias[col];
#pragma unroll
        for (int r = 0; r < 4; ++r)
          O[(size_t)(row + r) * ldo + col] = (bf16_t)fast_tanh(acc[i][j][r] + b);
      } else {  // EPI 4: h2 fragment-major fp8
        uint8_t* O = (uint8_t*)outp;
        const float b = bias[col];
        const int kb = col >> 6;
        const int khalf = (col >> 5) & 1;
        const int kin = col & 31;
#pragma unroll
        for (int r = 0; r < 4; ++r) {
          const int rw = row + r;
          O[(size_t)((rw >> 5) * 16 + kb) * 2048 +
            (khalf * 32 + (rw & 31)) * 32 + kin] =
              to_fp8(64.f * fast_tanh(acc[i][j][r] + b));
        }
      }
    }
  }
}

// ---------------------------------------------------------------------------
// Hbwd bf16 GEMM for 512-thread launch: 64x64 tile, BK=32, 8 waves arranged
// 2x4; per-wave 32x16 = 2x1 mfma 16x16x32.  dx store / dv atomicAdd(-C).
// Triple-buffer/counted-vmcnt pipeline (1 stage op per wave).
// ---------------------------------------------------------------------------
__device__ __forceinline__ void hbwd64_body(char* smem, int bx, int by,
                                            const bf16_t* A, int lda,
                                            const bf16_t* B, int ldb, int K,
                                            float* out, int ldo) {
  constexpr int BK = 32;
  bf16_t* As = (bf16_t*)smem;  // 3 x 64*32
  bf16_t* Bs = As + 3 * 2048;
  const int NT = K / BK;  // 20

  const int m0 = bx * 64;
  const int n0 = by * 64;
  const int tid = threadIdx.x;
  const int wave = tid >> 6;  // 0..7
  const int lane = tid & 63;
  const int wm = wave >> 2;   // 0..1
  const int wn = wave & 3;    // 0..3

  const int sr = lane >> 2;
  const int sk = (((lane & 3) ^ ((sr >> 1) & 3)) * 8);
  const int fr = lane & 15;
  const int fk = (((lane >> 4) ^ ((fr >> 1) & 3)) * 8);

  // waves 0..3 stage A rows, 4..7 stage B rows (1 g2l16 per wave per step)
  const int rbs = (wave & 3) * 16;
  const bf16_t* Sg = (wave < 4) ? A + (size_t)(m0 + rbs + sr) * lda + sk
                                : B + (size_t)(n0 + rbs + sr) * ldb + sk;
  bf16_t* Sl = ((wave < 4) ? As : Bs) + rbs * BK;

  f32x4_t acc[2] = {};

  g2l16(Sg, Sl);
  g2l16(Sg + BK, Sl + 2048);
  asm volatile("s_waitcnt vmcnt(1)" ::: "memory");
  __builtin_amdgcn_s_barrier();
  asm volatile("" ::: "memory");

  for (int t = 0; t < NT; ++t) {
    if (t + 2 < NT) g2l16(Sg + (t + 2) * BK, Sl + ((t + 2) % 3) * 2048);
    const bf16_t* Ab = As + (t % 3) * 2048;
    const bf16_t* Bb = Bs + (t % 3) * 2048;

    const bf16x8_t bb = *(const bf16x8_t*)(Bb + (wn * 16 + fr) * BK + fk);
#pragma unroll
    for (int u = 0; u < 2; ++u) {
      const bf16x8_t af =
          *(const bf16x8_t*)(Ab + (wm * 32 + u * 16 + fr) * BK + fk);
      acc[u] = __builtin_amdgcn_mfma_f32_16x16x32_bf16(af, bb, acc[u], 0, 0, 0);
    }
    if (t < NT - 1) {
      if (t + 2 < NT)
        asm volatile("s_waitcnt vmcnt(1)" ::: "memory");
      else
        asm volatile("s_waitcnt vmcnt(0)" ::: "memory");
      __builtin_amdgcn_s_barrier();
      asm volatile("" ::: "memory");
    }
  }

  // C/D layout (m89): col = lane&15, row = (lane>>4)*4 + reg
  const bool dx = (n0 < DIMD);
  const int col = n0 + wn * 16 + fr;
#pragma unroll
  for (int t = 0; t < 2; ++t) {
    const int row = m0 + wm * 32 + t * 16 + (lane >> 4) * 4;
#pragma unroll
    for (int r = 0; r < 4; ++r) {
      const size_t idx = (size_t)(row + r) * ldo + col;
      if (dx) out[idx] = acc[t][r];
      else atomicAdd(&out[idx], -acc[t][r]);  // dv_H shares with dvA
    }
  }
}

// ---------------------------------------------------------------------------
// A3 fused GEMM, MX-fp8, R18: 512 threads / 8 waves, BM=256, BN=128, BK=64.
// Wave grid 4x2: each wave 64x64 via 2x2 mfma 32x32x64 (acc[2][2] f32x16
// = 64 AGPRs).  NO LDS, NO BARRIERS: operands stream L2->reg as
// pre-swizzled fragments (AF = h2F 4MB, BF = Aw3T8F 16MB).
// Even/odd double-buffered loads (cur[8]/nxt[8] intx4); compiler
// auto-vmcnt via data dependence.  BN=128 = one u-period -> ocol = 128+by.
// ---------------------------------------------------------------------------
__device__ __forceinline__ void a3_body(int bx, int by, const uint8_t* AF,
                                        const uint8_t* BF, float* out,
                                        const float* ab3, const float* uvec) {
  constexpr int NT = 16;  // K / 64
  const int tid = threadIdx.x;
  const int wave = tid >> 6;  // 0..7
  const int lane = tid & 63;
  const int wm = wave >> 1;   // 0..3 : 64-row strip
  const int wn = wave & 1;    // 0..1 : 64-col strip
  const int rl = lane & 31;
  const int m0 = bx * 256;
  const int n0 = by * 128;

  // fragment stream base pointers (lane's 32B slice of each 2KB chunk)
  const uint8_t* bp[4];
#pragma unroll
  for (int i = 0; i < 2; ++i)
    bp[i] = AF + (size_t)(bx * 8 + wm * 2 + i) * 16 * 2048 + lane * 32;
#pragma unroll
  for (int j = 0; j < 2; ++j)
    bp[2 + j] = BF + (size_t)(by * 4 + wn * 2 + j) * 16 * 2048 + lane * 32;

  f32x16_t acc[2][2] = {};
  intx4_t cur[8], nxt[8];

#define A3_LOADSET(dst, off)                                   \
  _Pragma("unroll") for (int q = 0; q < 4; ++q) {              \
    dst[2 * q] = *(const intx4_t*)(bp[q] + (off));             \
    dst[2 * q + 1] = *(const intx4_t*)(bp[q] + (off) + 16);    \
  }

#define A3_MFMASET(S)                                                         \
  _Pragma("unroll") for (int i = 0; i < 2; ++i) {                             \
    intx8_t af = __builtin_shufflevector(S[2 * i], S[2 * i + 1], 0, 1, 2, 3,  \
                                         4, 5, 6, 7);                         \
    _Pragma("unroll") for (int j = 0; j < 2; ++j) {                           \
      intx8_t bf = __builtin_shufflevector(S[4 + 2 * j], S[5 + 2 * j], 0, 1,  \
                                           2, 3, 4, 5, 6, 7);                 \
      acc[i][j] = __builtin_amdgcn_mfma_scale_f32_32x32x64_f8f6f4(            \
          af, bf, acc[i][j], 0, 0, 0, 0x79797979, 0, 0x79797979);             \
    }                                                                         \
  }

  A3_LOADSET(cur, 0);
#pragma unroll 1
  for (int t = 0; t < NT; t += 2) {
    A3_LOADSET(nxt, (size_t)(t + 1) * 2048);
    A3_MFMASET(cur);
    if (t + 2 < NT) A3_LOADSET(cur, (size_t)(t + 2) * 2048);
    A3_MFMASET(nxt);
  }
#undef A3_LOADSET
#undef A3_MFMASET

  // epilogue: C/D col = lane&31, row = (reg&3)+8*(reg>>2)+4*(lane>>5).
  // block's 128 cols are one full u-period -> out column 128+by.
  const int q = lane >> 5;
  float uu[2], b3[2];
#pragma unroll
  for (int j = 0; j < 2; ++j) {
    uu[j] = uvec[wn * 64 + j * 32 + rl];
    b3[j] = ab3[n0 + wn * 64 + j * 32 + rl];
  }
  const int ocol = 128 + by;
#pragma unroll
  for (int i = 0; i < 2; ++i) {
    float s16[16];
#pragma unroll
    for (int r = 0; r < 16; ++r)
      s16[r] = fast_tanh(acc[i][0][r] + b3[0]) * uu[0] +
               fast_tanh(acc[i][1][r] + b3[1]) * uu[1];
#pragma unroll
    for (int r = 0; r < 16; ++r) s16[r] = dpp_sum32(s16[r]);
    if (rl == 31) {  // lanes 31 and 63 hold the two q-half sums
      const int rowb = m0 + wm * 64 + i * 32 + 4 * q;
#pragma unroll
      for (int r = 0; r < 16; ++r)
        atomicAdd(&out[(size_t)(rowb + (r & 3) + 8 * (r >> 2)) * 256 + ocol],
                  s16[r]);
    }
  }
}

// ---------------------------------------------------------------------------
// transposes / cvt helpers
// ---------------------------------------------------------------------------
__device__ __forceinline__ void tcvt_body(char* smem, const float* in,
                                          bf16_t* out, int R, int C, int bx,
                                          int by) {
  float(*t)[33] = (float(*)[33])smem;  // 4224 B
  const int c0 = bx * 32;
  const int r0 = by * 32;
  const int tx = threadIdx.x & 31;
  const int ty = threadIdx.x >> 5;
#pragma unroll
  for (int k = 0; k < 4; ++k)
    t[ty + k * 8][tx] = in[(size_t)(r0 + ty + k * 8) * C + c0 + tx];
  __syncthreads();
#pragma unroll
  for (int k = 0; k < 4; ++k)
    out[(size_t)(c0 + ty + k * 8) * R + r0 + tx] = (bf16_t)t[tx][ty + k * 8];
}

// Aw3 (1024 x 16384) -> fp8 x64, FRAGMENT-MAJOR (Aw3T8F).
// 128x128 tile per block (1024 blocks), float4 reads, cvt_pk packing,
// u32-transposed LDS [128][33]; drain writes fragment chunks:
//   chunk ((cb*16)+kb)*2048, byte (khalf*32 + col%32)*32 + k%32.
__device__ __forceinline__ void aw3t_body(char* smem, const float* Aw3,
                                          uint8_t* Aw3T8F, int b) {
  uint32_t(*T)[33] = (uint32_t(*)[33])smem;  // 16896 B
  const int ct = b & 127;
  const int rt = b >> 7;
  const size_t c0 = (size_t)ct * 128;
  const int r0 = rt * 128;
  const int tx = threadIdx.x & 31;  // col-chunk (4 f32)
  const int g = threadIdx.x >> 5;   // 0..7 row-group
#pragma unroll
  for (int k = 0; k < 4; ++k) {
    const int rr = r0 + 4 * g + 32 * k;
    const float4 v0 = *(const float4*)(Aw3 + (size_t)(rr + 0) * 16384 + c0 + 4 * tx);
    const float4 v1 = *(const float4*)(Aw3 + (size_t)(rr + 1) * 16384 + c0 + 4 * tx);
    const float4 v2 = *(const float4*)(Aw3 + (size_t)(rr + 2) * 16384 + c0 + 4 * tx);
    const float4 v3 = *(const float4*)(Aw3 + (size_t)(rr + 3) * 16384 + c0 + 4 * tx);
    const int r4 = g + 8 * k;  // row/4 within tile (k-dim of output)
    T[4 * tx + 0][r4] = pk4_fp8(64.f * v0.x, 64.f * v1.x, 64.f * v2.x, 64.f * v3.x);
    T[4 * tx + 1][r4] = pk4_fp8(64.f * v0.y, 64.f * v1.y, 64.f * v2.y, 64.f * v3.y);
    T[4 * tx + 2][r4] = pk4_fp8(64.f * v0.z, 64.f * v1.z, 64.f * v2.z, 64.f * v3.z);
    T[4 * tx + 3][r4] = pk4_fp8(64.f * v0.w, 64.f * v1.w, 64.f * v2.w, 64.f * v3.w);
  }
  __syncthreads();
  // T[cc][tx] = 4 fp8 bytes: col = c0+cc, k = r0+4*tx .. +3
  const int kb = (rt << 1) + (tx >> 4);     // k-block (64)
  const int khalf = (tx >> 3) & 1;          // k-half (32)
  const int kin = (tx & 7) << 2;            // k%32 (4-aligned)
#pragma unroll
  for (int k2 = 0; k2 < 16; ++k2) {
    const int cc = g + 8 * k2;
    const int cb = (ct << 2) + (cc >> 5);
    const int cin = cc & 31;
    *(uint32_t*)(Aw3T8F + (size_t)(cb * 16 + kb) * 2048 +
                 (khalf * 32 + cin) * 32 + kin) = T[cc][tx];
  }
}

// one wave handles one row: pre2 = h.Hw2; w_j = s*Hw2_j*(1-h_j^2)
__device__ __forceinline__ void hgrad_row(int row, const bf16_t* h,
                                          const float* Hw2, const float* Hb2,
                                          bf16_t* wout) {
  const int lane = threadIdx.x & 63;
  float hv[10], wv[10];
  float pre2 = 0.f;
#pragma unroll
  for (int t = 0; t < 10; ++t) {
    const int j = lane + t * 64;
    hv[t] = (float)h[(size_t)row * 640 + j];
    wv[t] = Hw2[j];
    pre2 += hv[t] * wv[t];
  }
#pragma unroll
  for (int d = 1; d < 64; d <<= 1) pre2 += __shfl_xor(pre2, d, 64);
  const float y = fast_tanh(pre2 + Hb2[0]);
  const float s = 1.f - y * y;
#pragma unroll
  for (int t = 0; t < 10; ++t) {
    const int j = lane + t * 64;
    wout[(size_t)row * 640 + j] = (bf16_t)(s * wv[t] * (1.f - hv[t] * hv[t]));
  }
}

// ---------------------------------------------------------------------------
// L0: inp cvt (1024) + Hw1T (160) + Aw1T (64) + Aw2T (512) + Hw1_bf cvt (160)
//     + zero-out (1024) = 2944 blocks
// ---------------------------------------------------------------------------
__global__ __launch_bounds__(256) void launch0(
    const float* __restrict__ inp, bf16_t* __restrict__ inp_bf,
    const float* __restrict__ Hw1, bf16_t* __restrict__ Hw1T,
    bf16_t* __restrict__ Hw1_bf, const float* __restrict__ Aw1,
    bf16_t* __restrict__ Aw1T, const float* __restrict__ Aw2,
    bf16_t* __restrict__ Aw2T, float* __restrict__ out) {
  __shared__ __align__(16) char smem[4224];
  int b = blockIdx.x;
  if (b < 1024) {
    const int i = b * 256 + threadIdx.x;
    const float4 v = ((const float4*)inp)[i];
    bf16x4_t o = {(bf16_t)v.x, (bf16_t)v.y, (bf16_t)v.z, (bf16_t)v.w};
    ((bf16x4_t*)inp_bf)[i] = o;
  } else if (b < 1184) {
    int s = b - 1024;
    tcvt_body(smem, Hw1, Hw1T, 256, 640, s % 20, s / 20);
  } else if (b < 1248) {
    int s = b - 1184;
    tcvt_body(smem, Aw1, Aw1T, 128, 512, s % 16, s / 16);
  } else if (b < 1760) {
    int s = b - 1248;
    tcvt_body(smem, Aw2, Aw2T, 512, 1024, s % 32, s / 32);
  } else if (b < 1920) {
    const int i = (b - 1760) * 256 + threadIdx.x;
    const float4 v = ((const float4*)Hw1)[i];
    bf16x4_t o = {(bf16_t)v.x, (bf16_t)v.y, (bf16_t)v.z, (bf16_t)v.w};
    ((bf16x4_t*)Hw1_bf)[i] = o;
  } else {
    const int i = (b - 1920) * 256 + threadIdx.x;
    ((float4*)out)[i] = make_float4(0.f, 0.f, 0.f, 0.f);
  }
}

// ---------------------------------------------------------------------------
// L1: Hfwd 64^2 (640) + A1 64^2 (512) + Aw3T tiles [0,512) = 1664 blocks
// ---------------------------------------------------------------------------
__global__ __launch_bounds__(256) void launch1(
    const bf16_t* __restrict__ inp_bf, const bf16_t* __restrict__ Hw1T,
    const float* __restrict__ Hb1, bf16_t* __restrict__ h_bf,
    const bf16_t* __restrict__ Aw1T, const float* __restrict__ Ab1,
    bf16_t* __restrict__ h1_bf, const float* __restrict__ Aw3,
    uint8_t* __restrict__ Aw3T8F) {
  __shared__ __align__(16) char smem[SMEM_G64];
  const int b = blockIdx.x;
  if (b < 640) {
    gemm64_body<0>(smem, b % 64, b / 64, inp_bf, 256, Hw1T, 256, 256, Hb1,
                   h_bf, 640);
  } else if (b < 1152) {
    const int i = b - 640;
    gemm64_body<0>(smem, i % 64, i / 64, inp_bf, 256, Aw1T, 128, 128, Ab1,
                   h1_bf, 512);
  } else {
    aw3t_body(smem, Aw3, Aw3T8F, b - 1152);  // tiles 0..511
  }
}

// ---------------------------------------------------------------------------
// L2: A2->h2F 64^2 (1024) + hgrad (1024) + Aw3T tiles [512,1024) = 2560
// ---------------------------------------------------------------------------
__global__ __launch_bounds__(256) void launch2(
    const bf16_t* __restrict__ h1_bf, const bf16_t* __restrict__ Aw2T,
    const float* __restrict__ Ab2, uint8_t* __restrict__ h2F,
    const bf16_t* __restrict__ h_bf, const float* __restrict__ Hw2,
    const float* __restrict__ Hb2, bf16_t* __restrict__ w_bf,
    const float* __restrict__ Aw3, uint8_t* __restrict__ Aw3T8F) {
  __shared__ __align__(16) char smem[SMEM_G64];
  const int b = blockIdx.x;
  if (b < 1024) {
    gemm64_body<4>(smem, b % 64, b / 64, h1_bf, 512, Aw2T, 512, 512, Ab2,
                   h2F, 0);
  } else if (b < 2048) {
    const int row = (b - 1024) * 4 + (threadIdx.x >> 6);
    hgrad_row(row, h_bf, Hw2, Hb2, w_bf);
  } else {
    aw3t_body(smem, Aw3, Aw3T8F, 512 + (b - 2048));  // tiles 512..1023
  }
}

// ---------------------------------------------------------------------------
// L3 (512 threads): Hbwd 64^2 8-wave (256) + A3 no-LDS (2048) = 2304.
// A3 swizzle: hardware XCD = p%8; each XCD owns 16 contiguous by values
// (B working set 16 x 128KB = 2MB -> L2-resident), bx varies slowest.
// ---------------------------------------------------------------------------
__global__ __launch_bounds__(512, 2) void launch3(
    const bf16_t* __restrict__ w_bf, const bf16_t* __restrict__ Hw1_bf,
    float* __restrict__ out, const uint8_t* __restrict__ h2F,
    const uint8_t* __restrict__ Aw3T8F, const float* __restrict__ Ab3,
    const float* __restrict__ uvec) {
  __shared__ __align__(16) char smem[SMEM3_BYTES];
  const int b = blockIdx.x;
  if (b < 256) {
    hbwd64_body(smem, b % 64, b / 64, w_bf, 640, Hw1_bf, 640, 640, out, 256);
  } else {
    const int p = b - 256;                          // 0..2047; hw XCD = p % 8
    const int by = (p & 7) * 16 + ((p >> 3) & 15);  // 0..127
    const int bx = p >> 7;                          // 0..15
    a3_body(bx, by, h2F, Aw3T8F, out, Ab3, uvec);
  }
}

// ---------------------------------------------------------------------------
extern "C" void kernel_launch(void* const* d_in, const int* in_sizes, int n_in,
                              void* d_out, int out_size, void* d_ws,
                              size_t ws_size, hipStream_t stream) {
  (void)in_sizes; (void)n_in; (void)out_size; (void)ws_size;
  const float* inp = (const float*)d_in[1];
  const float* Hw1 = (const float*)d_in[2];
  const float* Hb1 = (const float*)d_in[3];
  const float* Hw2 = (const float*)d_in[4];
  const float* Hb2 = (const float*)d_in[5];
  const float* Aw1 = (const float*)d_in[6];
  const float* Ab1 = (const float*)d_in[7];
  const float* Aw2 = (const float*)d_in[8];
  const float* Ab2 = (const float*)d_in[9];
  const float* Aw3 = (const float*)d_in[10];
  const float* Ab3 = (const float*)d_in[11];
  const float* u = (const float*)d_in[12];
  float* out = (float*)d_out;

  char* ws = (char*)d_ws;
  bf16_t* inp_bf = (bf16_t*)ws;    ws += (size_t)NROW * 256 * 2;
  bf16_t* Hw1_bf = (bf16_t*)ws;    ws += (size_t)256 * 640 * 2;
  bf16_t* Hw1T = (bf16_t*)ws;      ws += (size_t)640 * 256 * 2;
  bf16_t* Aw1T = (bf16_t*)ws;      ws += (size_t)512 * 128 * 2;
  bf16_t* Aw2T = (bf16_t*)ws;      ws += (size_t)1024 * 512 * 2;
  uint8_t* Aw3T8F = (uint8_t*)ws;  ws += (size_t)16384 * 1024;
  bf16_t* h_bf = (bf16_t*)ws;      ws += (size_t)NROW * 640 * 2;
  bf16_t* w_bf = (bf16_t*)ws;      ws += (size_t)NROW * 640 * 2;
  bf16_t* h1_bf = (bf16_t*)ws;     ws += (size_t)NROW * 512 * 2;
  uint8_t* h2F = (uint8_t*)ws;     ws += (size_t)NROW * 1024;

  launch0<<<2944, 256, 0, stream>>>(inp, inp_bf, Hw1, Hw1T, Hw1_bf, Aw1, Aw1T,
                                    Aw2, Aw2T, out);
  launch1<<<1664, 256, 0, stream>>>(inp_bf, Hw1T, Hb1, h_bf, Aw1T, Ab1, h1_bf,
                                    Aw3, Aw3T8F);
  launch2<<<2560, 256, 0, stream>>>(h1_bf, Aw2T, Ab2, h2F, h_bf, Hw2, Hb2,
                                    w_bf, Aw3, Aw3T8F);
  launch3<<<2304, 512, 0, stream>>>(w_bf, Hw1_bf, out, h2F, Aw3T8F, Ab3, u);
}